// Round 6
// baseline (537.638 us; speedup 1.0000x reference)
//
#include <hip/hip_runtime.h>
#include <cstdint>
#include <cstddef>

#define NNODES 100000
#define DIM 128
#define LDA 132   // LDS row stride (floats): 16B-aligned, breaks 128-float bank wrap

// =================== CSR build: count -> scan -> fill ===================

__global__ void count_dst(const int* __restrict__ dst, int* __restrict__ cnt, int E) {
  int e = blockIdx.x * 256 + threadIdx.x;
  if (e < E) atomicAdd(&cnt[dst[e]], 1);
}

// block-level exclusive scan over 1024-element chunks; bsum[b] = chunk total
__global__ void scan_blocks(const int* __restrict__ in, int* __restrict__ out,
                            int* __restrict__ bsum, int n) {
  __shared__ int wsum[4];
  const int tid = threadIdx.x;
  const int base = blockIdx.x * 1024 + tid * 4;
  int v0 = 0, v1 = 0, v2 = 0, v3 = 0;
  if (base + 0 < n) v0 = in[base + 0];
  if (base + 1 < n) v1 = in[base + 1];
  if (base + 2 < n) v2 = in[base + 2];
  if (base + 3 < n) v3 = in[base + 3];
  const int tsum = v0 + v1 + v2 + v3;
  const int lane = tid & 63, wid = tid >> 6;
  int x = tsum;
  for (int off = 1; off < 64; off <<= 1) {
    int y = __shfl_up(x, off, 64);
    if (lane >= off) x += y;
  }
  if (lane == 63) wsum[wid] = x;
  __syncthreads();
  int woff = 0;
  for (int w = 0; w < wid; ++w) woff += wsum[w];
  const int excl = woff + x - tsum;
  if (base + 0 < n) out[base + 0] = excl;
  if (base + 1 < n) out[base + 1] = excl + v0;
  if (base + 2 < n) out[base + 2] = excl + v0 + v1;
  if (base + 3 < n) out[base + 3] = excl + v0 + v1 + v2;
  if (tid == 255) bsum[blockIdx.x] = woff + x;
}

// single-block scan of up to 1024 block sums; bsum becomes exclusive offsets
__global__ void scan_top(int* __restrict__ bsum, int nb) {
  __shared__ int tmp[1024];
  const int tid = threadIdx.x;
  for (int i = tid; i < 1024; i += 256) tmp[i] = (i < nb) ? bsum[i] : 0;
  __syncthreads();
  for (int off = 1; off < 1024; off <<= 1) {
    int vals[4];
#pragma unroll
    for (int j = 0; j < 4; ++j) { int i = tid + j * 256; vals[j] = (i >= off) ? tmp[i - off] : 0; }
    __syncthreads();
#pragma unroll
    for (int j = 0; j < 4; ++j) { int i = tid + j * 256; tmp[i] += vals[j]; }
    __syncthreads();
  }
  for (int i = tid; i < nb; i += 256) {
    int orig = bsum[i];
    bsum[i] = tmp[i] - orig;   // exclusive
  }
}

__global__ void scan_add(int* __restrict__ out, const int* __restrict__ bsum, int n) {
  const int b = blockIdx.x;
  const int off = bsum[b];
  const int base = b * 1024 + threadIdx.x * 4;
#pragma unroll
  for (int j = 0; j < 4; ++j)
    if (base + j < n) out[base + j] += off;
}

__global__ void fill_csr(const int* __restrict__ src, const int* __restrict__ dst,
                         const int* __restrict__ rs, int* __restrict__ fill,
                         int* __restrict__ eidx, int E) {
  int e = blockIdx.x * 256 + threadIdx.x;
  if (e >= E) return;
  int d = dst[e];
  int p = rs[d] + atomicAdd(&fill[d], 1);
  eidx[p] = src[e];
}

__global__ void make_rnorm(const int* __restrict__ cnt, float* __restrict__ rnorm, int n) {
  int i = blockIdx.x * 256 + threadIdx.x;
  if (i < n) rnorm[i] = rsqrtf((float)cnt[i] + 1.0f);
}

// =================== gathers (32 threads / node, float4 cols) ===================

// out[i] = mean over incoming edges of x[src]
__global__ void gather_mean(const float* __restrict__ x, const int* __restrict__ rs,
                            const int* __restrict__ cnt, const int* __restrict__ eidx,
                            float* __restrict__ out, int n) {
  int gid = blockIdx.x * 256 + threadIdx.x;
  int i = gid >> 5;
  if (i >= n) return;
  int c = (gid & 31) << 2;
  int start = rs[i], m = cnt[i];
  float4 acc = {0.f, 0.f, 0.f, 0.f};
  for (int j = 0; j < m; ++j) {
    int s = eidx[start + j];
    float4 v = *(const float4*)(x + (size_t)s * DIM + c);
    acc.x += v.x; acc.y += v.y; acc.z += v.z; acc.w += v.w;
  }
  float inv = 1.0f / fmaxf((float)m, 1.0f);
  acc.x *= inv; acc.y *= inv; acc.z *= inv; acc.w *= inv;
  *(float4*)(out + (size_t)i * DIM + c) = acc;
}

// x2[i] = rnorm[i] * sum_e rnorm[s]*h[s] + h[i]*rnorm[i]^2 + bias
__global__ void gather_gcn(const float* __restrict__ h, const int* __restrict__ rs,
                           const int* __restrict__ cnt, const int* __restrict__ eidx,
                           const float* __restrict__ rnorm, const float* __restrict__ bias,
                           float* __restrict__ out, int n) {
  int gid = blockIdx.x * 256 + threadIdx.x;
  int i = gid >> 5;
  if (i >= n) return;
  int c = (gid & 31) << 2;
  int start = rs[i], m = cnt[i];
  float4 acc = {0.f, 0.f, 0.f, 0.f};
  for (int j = 0; j < m; ++j) {
    int s = eidx[start + j];
    float rn = rnorm[s];
    float4 v = *(const float4*)(h + (size_t)s * DIM + c);
    acc.x = fmaf(rn, v.x, acc.x);
    acc.y = fmaf(rn, v.y, acc.y);
    acc.z = fmaf(rn, v.z, acc.z);
    acc.w = fmaf(rn, v.w, acc.w);
  }
  float ri = rnorm[i];
  float invd = ri * ri;
  float4 hv = *(const float4*)(h + (size_t)i * DIM + c);
  float4 bv = *(const float4*)(bias + c);
  float4 o;
  o.x = fmaf(ri, acc.x, fmaf(invd, hv.x, bv.x));
  o.y = fmaf(ri, acc.y, fmaf(invd, hv.y, bv.y));
  o.z = fmaf(ri, acc.z, fmaf(invd, hv.z, bv.z));
  o.w = fmaf(ri, acc.w, fmaf(invd, hv.w, bv.w));
  *(float4*)(out + (size_t)i * DIM + c) = o;
}

// =================== f32 GEMM: out = act(pre + A @ W + b) ===================
// Thread t: 4 rows ((t>>4)*4), 8 cols ((t&15)*8). Per k-step-4: 4 ds_read_b128
// (16-way broadcast) + 8 global b128 of L1/L2-hot W + 128 FMAs -> VALU-bound.
// ALL vector-component access is explicit .x/.y/.z/.w — pointer-indexing into
// float4 regs defeats SROA and regenerates scalar ds_read_b32 (rounds 4/5, 76us).
// `pre`/`out` may alias element-for-element (same thread) — no restrict.

#define FMA8(av, wl, wh, i)                                        \
  accL[i].x = fmaf(av, wl.x, accL[i].x);                           \
  accL[i].y = fmaf(av, wl.y, accL[i].y);                           \
  accL[i].z = fmaf(av, wl.z, accL[i].z);                           \
  accL[i].w = fmaf(av, wl.w, accL[i].w);                           \
  accH[i].x = fmaf(av, wh.x, accH[i].x);                           \
  accH[i].y = fmaf(av, wh.y, accH[i].y);                           \
  accH[i].z = fmaf(av, wh.z, accH[i].z);                           \
  accH[i].w = fmaf(av, wh.w, accH[i].w);

template<int PRE, int BIAS, int RELU>
__global__ __launch_bounds__(256, 4) void gemm_f32(const float* __restrict__ A,
    const float* __restrict__ W, const float* __restrict__ bias,
    const float* pre, float* out, int nrows)
{
  __shared__ float Al[64 * LDA];   // 33 KB
  const int tid = threadIdx.x;
  const int rowblk = blockIdx.x * 64;

  for (int i = tid; i < 64 * 32; i += 256) {
    int r = i >> 5, c4 = (i & 31) << 2;
    int gr = rowblk + r;
    float4 v = {0.f, 0.f, 0.f, 0.f};
    if (gr < nrows) v = *(const float4*)(A + (size_t)gr * DIM + c4);
    *(float4*)&Al[r * LDA + c4] = v;
  }
  __syncthreads();

  const int rg = (tid >> 4) << 2;   // 4 rows
  const int c  = (tid & 15) << 3;   // 8 cols

  float4 accL[4], accH[4];
#pragma unroll
  for (int i = 0; i < 4; ++i) {
    accL[i] = (float4){0.f, 0.f, 0.f, 0.f};
    accH[i] = (float4){0.f, 0.f, 0.f, 0.f};
  }

  for (int k = 0; k < DIM; k += 4) {
    float4 a0 = *(const float4*)&Al[(rg + 0) * LDA + k];
    float4 a1 = *(const float4*)&Al[(rg + 1) * LDA + k];
    float4 a2 = *(const float4*)&Al[(rg + 2) * LDA + k];
    float4 a3 = *(const float4*)&Al[(rg + 3) * LDA + k];
    float4 w0L = *(const float4*)(W + (k + 0) * DIM + c);
    float4 w0H = *(const float4*)(W + (k + 0) * DIM + c + 4);
    float4 w1L = *(const float4*)(W + (k + 1) * DIM + c);
    float4 w1H = *(const float4*)(W + (k + 1) * DIM + c + 4);
    float4 w2L = *(const float4*)(W + (k + 2) * DIM + c);
    float4 w2H = *(const float4*)(W + (k + 2) * DIM + c + 4);
    float4 w3L = *(const float4*)(W + (k + 3) * DIM + c);
    float4 w3H = *(const float4*)(W + (k + 3) * DIM + c + 4);

    FMA8(a0.x, w0L, w0H, 0)  FMA8(a0.y, w1L, w1H, 0)
    FMA8(a0.z, w2L, w2H, 0)  FMA8(a0.w, w3L, w3H, 0)
    FMA8(a1.x, w0L, w0H, 1)  FMA8(a1.y, w1L, w1H, 1)
    FMA8(a1.z, w2L, w2H, 1)  FMA8(a1.w, w3L, w3H, 1)
    FMA8(a2.x, w0L, w0H, 2)  FMA8(a2.y, w1L, w1H, 2)
    FMA8(a2.z, w2L, w2H, 2)  FMA8(a2.w, w3L, w3H, 2)
    FMA8(a3.x, w0L, w0H, 3)  FMA8(a3.y, w1L, w1H, 3)
    FMA8(a3.z, w2L, w2H, 3)  FMA8(a3.w, w3L, w3H, 3)
  }

  float4 bL = {0.f, 0.f, 0.f, 0.f}, bH = {0.f, 0.f, 0.f, 0.f};
  if (BIAS) {
    bL = *(const float4*)(bias + c);
    bH = *(const float4*)(bias + c + 4);
  }
#pragma unroll
  for (int i = 0; i < 4; ++i) {
    int gr = rowblk + rg + i;
    if (gr < nrows) {
      size_t off = (size_t)gr * DIM + c;
      float4 pL = {0.f, 0.f, 0.f, 0.f}, pH = {0.f, 0.f, 0.f, 0.f};
      if (PRE) {
        pL = *(const float4*)(pre + off);
        pH = *(const float4*)(pre + off + 4);
      }
      float4 oL, oH;
      oL.x = accL[i].x + bL.x + pL.x;  oL.y = accL[i].y + bL.y + pL.y;
      oL.z = accL[i].z + bL.z + pL.z;  oL.w = accL[i].w + bL.w + pL.w;
      oH.x = accH[i].x + bH.x + pH.x;  oH.y = accH[i].y + bH.y + pH.y;
      oH.z = accH[i].z + bH.z + pH.z;  oH.w = accH[i].w + bH.w + pH.w;
      if (RELU) {
        oL.x = fmaxf(oL.x, 0.f); oL.y = fmaxf(oL.y, 0.f);
        oL.z = fmaxf(oL.z, 0.f); oL.w = fmaxf(oL.w, 0.f);
        oH.x = fmaxf(oH.x, 0.f); oH.y = fmaxf(oH.y, 0.f);
        oH.z = fmaxf(oH.z, 0.f); oH.w = fmaxf(oH.w, 0.f);
      }
      *(float4*)(out + off) = oL;
      *(float4*)(out + off + 4) = oH;
    }
  }
}

// =================== host ===================

extern "C" void kernel_launch(void* const* d_in, const int* in_sizes, int n_in,
                              void* d_out, int out_size, void* d_ws, size_t ws_size,
                              hipStream_t stream) {
  const float* emb = (const float*)d_in[0];
  const float* Wd  = (const float*)d_in[1];
  const float* bd  = (const float*)d_in[2];
  const float* Wg  = (const float*)d_in[3];
  const float* bg  = (const float*)d_in[4];
  const float* Wu  = (const float*)d_in[5];
  const float* bu  = (const float*)d_in[6];
  const int* d2u = (const int*)d_in[7];
  const int* sle = (const int*)d_in[8];
  const int* u2d = (const int*)d_in[9];
  const int E1 = in_sizes[7] / 2;   // 100000
  const int E2 = in_sizes[8] / 2;   // 600000
  const int E3 = in_sizes[9] / 2;   // 100000
  const int N  = NNODES;
  const size_t nd = (size_t)N * DIM;

  // ws layout: bufA[nd f32] | cntA,fillA,cntB,fillB,cntC,fillC [6N int] |
  //            rsA,rsB,rsC [3N int] | eidxA[E1] eidxB[E2] eidxC[E3] | rnorm[N f32] |
  //            bsumA,bsumB,bsumC [3*1024 int]   (~58.7 MB total)
  float* bufA = (float*)d_ws;
  int* cntA  = (int*)(bufA + nd);
  int* fillA = cntA + N;
  int* cntB  = fillA + N;
  int* fillB = cntB + N;
  int* cntC  = fillB + N;
  int* fillC = cntC + N;
  int* rsA   = fillC + N;
  int* rsB   = rsA + N;
  int* rsC   = rsB + N;
  int* eidxA = rsC + N;
  int* eidxB = eidxA + E1;
  int* eidxC = eidxB + E2;
  float* rnorm = (float*)(eidxC + E3);
  int* bsumA = (int*)(rnorm + N);
  int* bsumB = bsumA + 1024;
  int* bsumC = bsumB + 1024;
  float* bufB = (float*)d_out;

  const int gemm_blocks = (N + 63) / 64;
  const int nscan = (N + 1023) / 1024;            // 98
  const int ngather = (N * 32 + 255) / 256;       // 12500

  // ---- build all three CSRs ----
  (void)hipMemsetAsync(cntA, 0, (size_t)6 * N * sizeof(int), stream);
  count_dst<<<(E1 + 255) / 256, 256, 0, stream>>>(d2u + E1, cntA, E1);
  count_dst<<<(E2 + 255) / 256, 256, 0, stream>>>(sle + E2, cntB, E2);
  count_dst<<<(E3 + 255) / 256, 256, 0, stream>>>(u2d + E3, cntC, E3);
  make_rnorm<<<(N + 255) / 256, 256, 0, stream>>>(cntB, rnorm, N);
  scan_blocks<<<nscan, 256, 0, stream>>>(cntA, rsA, bsumA, N);
  scan_blocks<<<nscan, 256, 0, stream>>>(cntB, rsB, bsumB, N);
  scan_blocks<<<nscan, 256, 0, stream>>>(cntC, rsC, bsumC, N);
  scan_top<<<1, 256, 0, stream>>>(bsumA, nscan);
  scan_top<<<1, 256, 0, stream>>>(bsumB, nscan);
  scan_top<<<1, 256, 0, stream>>>(bsumC, nscan);
  scan_add<<<nscan, 256, 0, stream>>>(rsA, bsumA, N);
  scan_add<<<nscan, 256, 0, stream>>>(rsB, bsumB, N);
  scan_add<<<nscan, 256, 0, stream>>>(rsC, bsumC, N);
  fill_csr<<<(E1 + 255) / 256, 256, 0, stream>>>(d2u, d2u + E1, rsA, fillA, eidxA, E1);
  fill_csr<<<(E2 + 255) / 256, 256, 0, stream>>>(sle, sle + E2, rsB, fillB, eidxB, E2);
  fill_csr<<<(E3 + 255) / 256, 256, 0, stream>>>(u2d, u2d + E3, rsC, fillC, eidxC, E3);

  // ---- stage A: agg1 = segment_mean(emb) ; x1 = relu(emb + agg1@Wd + bd) ----
  gather_mean<<<ngather, 256, 0, stream>>>(emb, rsA, cntA, eidxA, bufA, N);
  gemm_f32<1, 1, 1><<<gemm_blocks, 256, 0, stream>>>(bufA, Wd, bd, emb, bufB, N);   // x1 -> d_out

  // ---- stage B: h = x1@Wg ; x2 = gcn(h) ----
  gemm_f32<0, 0, 0><<<gemm_blocks, 256, 0, stream>>>(bufB, Wg, nullptr, nullptr, bufA, N);  // h -> ws
  gather_gcn<<<ngather, 256, 0, stream>>>(bufA, rsB, cntB, eidxB, rnorm, bg, bufB, N);       // x2 -> d_out

  // ---- stage C: agg2 = segment_mean(x2) ; out = relu(x2 + agg2@Wu + bu) ----
  gather_mean<<<ngather, 256, 0, stream>>>(bufB, rsC, cntC, eidxC, bufA, N);
  gemm_f32<1, 1, 1><<<gemm_blocks, 256, 0, stream>>>(bufA, Wu, bu, bufB, bufB, N);
}